// Round 1
// baseline (6821.095 us; speedup 1.0000x reference)
//
#include <hip/hip_runtime.h>
#include <math.h>

#define F 128

typedef float floatx4 __attribute__((ext_vector_type(4)));
typedef short shortx8 __attribute__((ext_vector_type(8)));

__device__ __forceinline__ unsigned short f2bf(float f) {
    union { float f; unsigned u; } v; v.f = f;
    unsigned r = (v.u + 0x7FFFu + ((v.u >> 16) & 1u)) >> 16;
    return (unsigned short)r;
}

__device__ __forceinline__ float sigm(float x) { return 1.f / (1.f + __expf(-x)); }

// ---------------------------------------------------------------------------
// C[M,128(:ldC)] = bf16( A[M,128] ) @ bf16( W[128,128] )^T + bias[128] (+ addend[M,128])
// block = 256 threads (4 waves), BM=64 rows, full K=128 staged in LDS.
// mfma_f32_16x16x32_bf16: A[m=lane&15][k=quad*8+j], B[k=quad*8+j][n=lane&15],
// D col=lane&15, row=quad*4+reg (per measured m89 layouts).
// ---------------------------------------------------------------------------
__global__ __launch_bounds__(256) void gemm_aw(
    const float* __restrict__ A, const float* __restrict__ W,
    const float* __restrict__ bias, const float* __restrict__ addend,
    float* __restrict__ C, int M, int ldC)
{
    __shared__ unsigned short As[64 * 136];
    __shared__ unsigned short Ws[128 * 136];
    const int tid = threadIdx.x;
    const long base = (long)blockIdx.x * 64;

    // stage W: 128x128 fp32 -> bf16 LDS (4096 float4 / 256 thr = 16 iters)
    for (int it = 0; it < 16; ++it) {
        int fidx = it * 256 + tid;
        int row = fidx >> 5, c4 = (fidx & 31) * 4;
        float4 wv = *(const float4*)&W[row * 128 + c4];
        unsigned short* p = &Ws[row * 136 + c4];
        p[0] = f2bf(wv.x); p[1] = f2bf(wv.y); p[2] = f2bf(wv.z); p[3] = f2bf(wv.w);
    }
    // stage A tile: 64x128 (2048 float4 / 256 thr = 8 iters), zero-pad OOB rows
    for (int it = 0; it < 8; ++it) {
        int fidx = it * 256 + tid;
        int row = fidx >> 5, c4 = (fidx & 31) * 4;
        long grow = base + row;
        float4 av = make_float4(0.f, 0.f, 0.f, 0.f);
        if (grow < M) av = *(const float4*)&A[grow * 128 + c4];
        unsigned short* p = &As[row * 136 + c4];
        p[0] = f2bf(av.x); p[1] = f2bf(av.y); p[2] = f2bf(av.z); p[3] = f2bf(av.w);
    }
    __syncthreads();

    const int w = tid >> 6, lane = tid & 63;
    const int ml = lane & 15, quad = lane >> 4;
    floatx4 acc[8];
#pragma unroll
    for (int t = 0; t < 8; ++t) acc[t] = (floatx4)(0.f);

    const int arow = (w * 16 + ml) * 136;
#pragma unroll
    for (int kk = 0; kk < 4; ++kk) {
        shortx8 a = *(const shortx8*)&As[arow + kk * 32 + quad * 8];
#pragma unroll
        for (int t = 0; t < 8; ++t) {
            shortx8 b = *(const shortx8*)&Ws[(t * 16 + ml) * 136 + kk * 32 + quad * 8];
            acc[t] = __builtin_amdgcn_mfma_f32_16x16x32_bf16(a, b, acc[t], 0, 0, 0);
        }
    }

#pragma unroll
    for (int t = 0; t < 8; ++t) {
        int gcol = t * 16 + ml;
        float bv = bias[gcol];
#pragma unroll
        for (int r = 0; r < 4; ++r) {
            long grow = base + w * 16 + quad * 4 + r;
            if (grow < M) {
                float v = acc[t][r] + bv;
                if (addend) v += addend[grow * 128 + gcol];
                C[grow * (long)ldC + gcol] = v;
            }
        }
    }
}

// ---------------------------------------------------------------------------
// pass1: msg[e] += G[i].s0 + G[j].s1 ; sig_sum[i] += sigmoid(msg)
// 32 lanes per edge (float4/lane), 8 edges per block.
// ---------------------------------------------------------------------------
__global__ __launch_bounds__(256) void edge_pass1(
    const int* __restrict__ ii, const int* __restrict__ jj,
    const float* __restrict__ G, float* __restrict__ msg,
    float* __restrict__ sig_sum, int E)
{
    int sub = threadIdx.x >> 5, lane = threadIdx.x & 31;
    long e = (long)blockIdx.x * 8 + sub;
    if (e >= E) return;
    long i = ii[e], j = jj[e];
    int c = lane * 4;
    float4 m = *(float4*)&msg[e * 128 + c];
    float4 gi = *(const float4*)&G[i * 384 + c];
    float4 gj = *(const float4*)&G[j * 384 + 128 + c];
    m.x += gi.x + gj.x; m.y += gi.y + gj.y; m.z += gi.z + gj.z; m.w += gi.w + gj.w;
    *(float4*)&msg[e * 128 + c] = m;
    float* ss = &sig_sum[i * 128 + c];
    unsafeAtomicAdd(ss + 0, sigm(m.x));
    unsafeAtomicAdd(ss + 1, sigm(m.y));
    unsafeAtomicAdd(ss + 2, sigm(m.z));
    unsafeAtomicAdd(ss + 3, sigm(m.w));
}

// ---------------------------------------------------------------------------
// pass2: agg[i] += sigmoid(msg)*G[j].s2/(sig_sum[i]+eps);
//        e_out[e] = e_in[e] + silu(scale*msg + shift)   (e_out aliases msg!)
// ---------------------------------------------------------------------------
__global__ __launch_bounds__(256) void edge_pass2(
    const int* __restrict__ ii, const int* __restrict__ jj,
    const float* __restrict__ G, const float* msg,
    const float* __restrict__ sig_sum, const float* __restrict__ e_in,
    float* __restrict__ agg, float* e_out,
    const float* __restrict__ scale, const float* __restrict__ shift, int E)
{
    int sub = threadIdx.x >> 5, lane = threadIdx.x & 31;
    long e = (long)blockIdx.x * 8 + sub;
    if (e >= E) return;
    long i = ii[e], j = jj[e];
    int c = lane * 4;
    float4 m  = *(const float4*)&msg[e * 128 + c];
    float4 ss = *(const float4*)&sig_sum[i * 128 + c];
    float4 u  = *(const float4*)&G[j * 384 + 256 + c];
    float4 ei = *(const float4*)&e_in[e * 128 + c];
    float4 sc = *(const float4*)&scale[c];
    float4 sh = *(const float4*)&shift[c];
    float* ag = &agg[i * 128 + c];
    float n0 = sigm(m.x) * u.x / (ss.x + 1e-9f);
    float n1 = sigm(m.y) * u.y / (ss.y + 1e-9f);
    float n2 = sigm(m.z) * u.z / (ss.z + 1e-9f);
    float n3 = sigm(m.w) * u.w / (ss.w + 1e-9f);
    unsafeAtomicAdd(ag + 0, n0);
    unsafeAtomicAdd(ag + 1, n1);
    unsafeAtomicAdd(ag + 2, n2);
    unsafeAtomicAdd(ag + 3, n3);
    float b0 = sc.x * m.x + sh.x, b1 = sc.y * m.y + sh.y;
    float b2 = sc.z * m.z + sh.z, b3 = sc.w * m.w + sh.w;
    float4 o;
    o.x = ei.x + b0 * sigm(b0);
    o.y = ei.y + b1 * sigm(b1);
    o.z = ei.z + b2 * sigm(b2);
    o.w = ei.w + b3 * sigm(b3);
    *(float4*)&e_out[e * 128 + c] = o;
}

// column sums + sumsq over X[M,128] -> sums[0:128]=sum, sums[128:256]=sumsq
__global__ __launch_bounds__(256) void col_stats(
    const float* __restrict__ X, int M, float* __restrict__ sums)
{
    int col = threadIdx.x & 127, half = threadIdx.x >> 7;
    float s1 = 0.f, s2 = 0.f;
    for (long r = (long)blockIdx.x * 2 + half; r < M; r += (long)gridDim.x * 2) {
        float v = X[r * 128 + col];
        s1 += v; s2 += v * v;
    }
    __shared__ float red[512];
    red[threadIdx.x] = s1;
    red[256 + threadIdx.x] = s2;
    __syncthreads();
    if (threadIdx.x < 128) {
        unsafeAtomicAdd(&sums[col], red[threadIdx.x] + red[threadIdx.x + 128]);
        unsafeAtomicAdd(&sums[128 + col], red[256 + threadIdx.x] + red[256 + threadIdx.x + 128]);
    }
}

__global__ void bn_finalize(const float* __restrict__ sums,
                            const float* __restrict__ gamma, const float* __restrict__ beta,
                            float* __restrict__ sc, float* __restrict__ sh, float invM)
{
    int c = threadIdx.x;
    float mu = sums[c] * invM;
    float var = sums[128 + c] * invM - mu * mu;
    float inv = rsqrtf(var + 1e-5f);
    float s = gamma[c] * inv;
    sc[c] = s;
    sh[c] = beta[c] - mu * s;
}

// out = X + silu(scale*h + shift)   (out may alias X: same-index RMW)
__global__ __launch_bounds__(256) void node_final(
    const float* X, const float* __restrict__ h,
    const float* __restrict__ sc, const float* __restrict__ sh,
    float* out, long total4)
{
    long idx = (long)blockIdx.x * 256 + threadIdx.x;
    if (idx >= total4) return;
    int c = ((int)(idx & 31)) * 4;
    float4 xv = ((const float4*)X)[idx];
    float4 hv = ((const float4*)h)[idx];
    float4 scv = *(const float4*)&sc[c];
    float4 shv = *(const float4*)&sh[c];
    float b0 = scv.x * hv.x + shv.x, b1 = scv.y * hv.y + shv.y;
    float b2 = scv.z * hv.z + shv.z, b3 = scv.w * hv.w + shv.w;
    float4 o;
    o.x = xv.x + b0 * sigm(b0);
    o.y = xv.y + b1 * sigm(b1);
    o.z = xv.z + b2 * sigm(b2);
    o.w = xv.w + b3 * sigm(b3);
    ((float4*)out)[idx] = o;
}

// ---------------------------------------------------------------------------
static void run_conv(const int* idx, int Em, int Nn,
                     const float* X, const float* Efeat,
                     const float* W, const float* b,
                     const float* bng, const float* bnb,
                     float* msgbuf,    // [Em,128]: EW -> edge_msg -> e_out (in place)
                     float* x_out,     // [Nn,128] (may alias X)
                     float* G, float* sig_sum, float* agg, float* stats,
                     hipStream_t stream)
{
    const int* ii = idx;
    const int* jj = idx + Em;
    hipMemsetAsync(sig_sum, 0, (size_t)Nn * 128 * 4, stream);
    hipMemsetAsync(agg, 0, (size_t)Nn * 128 * 4, stream);
    hipMemsetAsync(stats, 0, 1024 * 4, stream);

    int gN = (Nn + 63) / 64, gE = (Em + 63) / 64;
    // node projections: G[n] = [x@W0^T+b0 | x@W1^T+b1 | x@W4^T+b4]
    gemm_aw<<<gN, 256, 0, stream>>>(X, W + 0 * 16384, b + 0 * 128, nullptr, G + 0,   Nn, 384);
    gemm_aw<<<gN, 256, 0, stream>>>(X, W + 1 * 16384, b + 1 * 128, nullptr, G + 128, Nn, 384);
    gemm_aw<<<gN, 256, 0, stream>>>(X, W + 4 * 16384, b + 4 * 128, nullptr, G + 256, Nn, 384);
    // EW = e@W2^T + b2 into msg buffer
    gemm_aw<<<gE, 256, 0, stream>>>(Efeat, W + 2 * 16384, b + 2 * 128, nullptr, msgbuf, Em, 128);

    edge_pass1<<<(Em + 7) / 8, 256, 0, stream>>>(ii, jj, G, msgbuf, sig_sum, Em);
    col_stats<<<1024, 256, 0, stream>>>(msgbuf, Em, stats);
    bn_finalize<<<1, 128, 0, stream>>>(stats, bng, bnb, stats + 256, stats + 384, 1.f / Em);
    edge_pass2<<<(Em + 7) / 8, 256, 0, stream>>>(ii, jj, G, msgbuf, sig_sum, Efeat,
                                                 agg, msgbuf, stats + 256, stats + 384, Em);
    // h = X@W3^T + b3 + agg  (reuse G as h storage; G dead after pass2)
    float* h = G;
    gemm_aw<<<gN, 256, 0, stream>>>(X, W + 3 * 16384, b + 3 * 128, agg, h, Nn, 128);
    col_stats<<<1024, 256, 0, stream>>>(h, Nn, stats + 512);
    bn_finalize<<<1, 128, 0, stream>>>(stats + 512, bng + 128, bnb + 128,
                                       stats + 768, stats + 896, 1.f / Nn);
    long tot4 = (long)Nn * 32;
    node_final<<<(int)((tot4 + 255) / 256), 256, 0, stream>>>(X, h, stats + 768, stats + 896,
                                                              x_out, tot4);
}

extern "C" void kernel_launch(void* const* d_in, const int* in_sizes, int n_in,
                              void* d_out, int out_size, void* d_ws, size_t ws_size,
                              hipStream_t stream)
{
    (void)in_sizes; (void)n_in; (void)out_size; (void)ws_size;
    const int*   g_idx  = (const int*)d_in[0];    // [2, 400000]
    const int*   lg_idx = (const int*)d_in[1];    // [2, 800000]
    const float* x   = (const float*)d_in[2];     // [50000,128]
    const float* y   = (const float*)d_in[3];     // [400000,128]
    const float* z   = (const float*)d_in[4];     // [800000,128]
    const float* W1  = (const float*)d_in[5];
    const float* b1  = (const float*)d_in[6];
    const float* bng1 = (const float*)d_in[7];
    const float* bnb1 = (const float*)d_in[8];
    const float* W2  = (const float*)d_in[9];
    const float* b2  = (const float*)d_in[10];
    const float* bng2 = (const float*)d_in[11];
    const float* bnb2 = (const float*)d_in[12];

    float* out   = (float*)d_out;
    float* x_out = out;                          // 50000*128
    float* y_reg = out + (long)50000 * 128;      // 400000*128: msg1 -> m -> y_out
    float* z_reg = y_reg + (long)400000 * 128;   // 800000*128: msg2 -> z_out

    float* G       = (float*)d_ws;               // 400000*384 floats (614.4 MB)
    float* sig_sum = G + (long)400000 * 384;     // 400000*128
    float* agg     = sig_sum + (long)400000 * 128;
    float* stats   = agg + (long)400000 * 128;   // 1024 floats

    // conv1 on graph g: (x, y) -> (x_out, m in y_reg)
    run_conv(g_idx, 400000, 50000, x, y, W1, b1, bng1, bnb1,
             y_reg, x_out, G, sig_sum, agg, stats, stream);
    // conv2 on line graph: nodes = edges of g (features m), edges = z
    run_conv(lg_idx, 800000, 400000, y_reg, z, W2, b2, bng2, bnb2,
             z_reg, y_reg, G, sig_sum, agg, stats, stream);
}